// Round 1
// baseline (2306.351 us; speedup 1.0000x reference)
//
#include <hip/hip_runtime.h>
#include <math.h>

#define B_    8
#define NIN_  4096
#define P_    1024
#define K_    16
#define F_    64
#define CH_   67      // 3 + F
#define CPF_  64
#define CIN_  128
#define C_    128

// ---- ws float-offset layout (BN scale/shift), then idx ints at byte 8192 ----
#define S_PF1  0
#define SH_PF1 64
#define S_PF2  128
#define SH_PF2 192
#define S_C1   256
#define SH_C1  512
#define S_C2   768
#define SH_C2  1024
#define S_C3   1280
#define SH_C3  1536
#define S_F    1792
#define SH_F   1920

// ---------------------------------------------------------------------------
// Kernel 0: fold BN params (stacked [g,b,m,v] rows) into scale/shift
// ---------------------------------------------------------------------------
__global__ void bn_prep(const float* __restrict__ bn_pf1, const float* __restrict__ bn_pf2,
                        const float* __restrict__ bn_c1,  const float* __restrict__ bn_c2,
                        const float* __restrict__ bn_c3,  const float* __restrict__ bn_f,
                        float* __restrict__ wsf) {
    int t = threadIdx.x;
    const float* src; int nch, c, so, sho;
    if (t < 64)       { src = bn_pf1; nch = 64;  c = t;        so = S_PF1; sho = SH_PF1; }
    else if (t < 128) { src = bn_pf2; nch = 64;  c = t - 128 + 64; so = S_PF2; sho = SH_PF2; c = t - 64; }
    else if (t < 384) { src = bn_c1;  nch = 256; c = t - 128;  so = S_C1;  sho = SH_C1; }
    else if (t < 640) { src = bn_c2;  nch = 256; c = t - 384;  so = S_C2;  sho = SH_C2; }
    else if (t < 896) { src = bn_c3;  nch = 256; c = t - 640;  so = S_C3;  sho = SH_C3; }
    else              { src = bn_f;   nch = 128; c = t - 896;  so = S_F;   sho = SH_F;  }
    float g = src[c], b = src[nch + c], m = src[2 * nch + c], v = src[3 * nch + c];
    float s = g * rsqrtf(v + 1e-3f);
    wsf[so + c]  = s;
    wsf[sho + c] = b - m * s;
}

// ---------------------------------------------------------------------------
// Kernel 1: exact KNN (stable top-32, dilated by 2 -> 16 idx per query)
// One block = one batch b x 32 queries. Candidates cached in LDS in 2 halves.
// d2 computed bitwise-identically to the reference:
//   qq = ((q0*q0)+(q1*q1))+(q2*q2); pp likewise; e = ((q0p0)+(q1p1))+(q2p2)
//   d2 = (qq + pp) - (2*e)          [all round-to-nearest, no FMA]
// ---------------------------------------------------------------------------
__global__ __launch_bounds__(64) void knn_kernel(const float* __restrict__ inp,
                                                 int* __restrict__ idxo) {
    __shared__ float4 pc[2048];
    __shared__ float  ld[32][32];
    __shared__ int    li[32][32];

    const int b  = blockIdx.x >> 5;        // 32 chunks per batch
    const int ch = blockIdx.x & 31;
    const int t  = threadIdx.x;
    const int qi = (ch << 5) | (t & 31);   // query index (valid for t<32)
    const float* base = inp + (size_t)b * NIN_ * CH_;

    const float q0 = base[(size_t)qi * CH_ + 0];
    const float q1 = base[(size_t)qi * CH_ + 1];
    const float q2 = base[(size_t)qi * CH_ + 2];
    const float qq = __fadd_rn(__fadd_rn(__fmul_rn(q0, q0), __fmul_rn(q1, q1)),
                               __fmul_rn(q2, q2));

    if (t < 32) {
#pragma unroll
        for (int s = 0; s < 32; ++s) { ld[s][t] = 1e30f; li[s][t] = 0; }
    }
    float kth = 1e30f;

    for (int half = 0; half < 2; ++half) {
        __syncthreads();
        const int j0 = half * 2048;
        for (int j = t; j < 2048; j += 64) {
            const float* r = base + (size_t)(j0 + j) * CH_;
            float x = r[0], y = r[1], z = r[2];
            float pp = __fadd_rn(__fadd_rn(__fmul_rn(x, x), __fmul_rn(y, y)),
                                 __fmul_rn(z, z));
            pc[j] = make_float4(x, y, z, pp);
        }
        __syncthreads();
        if (t < 32) {
#pragma unroll 4
            for (int j = 0; j < 2048; ++j) {
                float4 p = pc[j];
                float e  = __fadd_rn(__fadd_rn(__fmul_rn(q0, p.x), __fmul_rn(q1, p.y)),
                                     __fmul_rn(q2, p.z));
                float d2 = __fsub_rn(__fadd_rn(qq, p.w), __fmul_rn(2.0f, e));
                if (d2 < kth) {
                    int s = 31;
                    while (s > 0 && ld[s - 1][t] > d2) {
                        ld[s][t] = ld[s - 1][t];
                        li[s][t] = li[s - 1][t];
                        --s;
                    }
                    ld[s][t] = d2;
                    li[s][t] = j0 + j;
                    kth = ld[31][t];
                }
            }
        }
    }
    if (t < 32) {
        int* op = idxo + (((size_t)b << 10) | qi) * K_;
#pragma unroll
        for (int r = 0; r < K_; ++r) op[r] = li[2 * r][t];
    }
}

// ---------------------------------------------------------------------------
// Kernel 2: full per-point pipeline. One wave (64 lanes) per point; 2 points
// per 128-thread block. No __syncthreads: each wave owns a private LDS slice
// and relies on in-order per-wave LDS ops.
// ---------------------------------------------------------------------------
__global__ __launch_bounds__(128) void pipeline_kernel(
    const float* __restrict__ inp, const int* __restrict__ idx,
    const float* __restrict__ Wpf1, const float* __restrict__ bpf1,
    const float* __restrict__ Wpf2, const float* __restrict__ bpf2,
    const float* __restrict__ Wc1,  const float* __restrict__ bc1,
    const float* __restrict__ Wc2,  const float* __restrict__ bc2,
    const float* __restrict__ Wc3,  const float* __restrict__ bc3,
    const float* __restrict__ Wdf,  const float* __restrict__ Wpw,
    const float* __restrict__ bf,   const float* __restrict__ wsf,
    float* __restrict__ out) {

    __shared__ float pnbf[2][48];        // p_nb flat [k*3+d]
    __shared__ float h1l[2][16][64];     // h after pf1+BN
    __shared__ float feat[2][16][128];   // [h2 | f_nb]
    __shared__ float xb[2][2][256];      // ping-pong x buffers
    __shared__ float dwl[2][256];        // dw flat

    const int w  = threadIdx.x >> 6;
    const int l  = threadIdx.x & 63;
    const int ng = blockIdx.x * 2 + w;   // global point id (b*1024+n)
    const int b  = ng >> 10;
    const int n  = ng & 1023;
    const float* brow = inp + (size_t)b * NIN_ * CH_;
    const int* ip = idx + (size_t)ng * K_;

    const float q0 = brow[(size_t)n * CH_ + 0];
    const float q1 = brow[(size_t)n * CH_ + 1];
    const float q2 = brow[(size_t)n * CH_ + 2];

    // ---- Stage A: gather neighbor rows -> pnbf (xyz - q) and feat[:,64:128]
    for (int k = 0; k < 16; ++k) {
        const float* r = brow + (size_t)ip[k] * CH_;
        float v = r[l];
        if (l < 3) {
            float qv = (l == 0) ? q0 : ((l == 1) ? q1 : q2);
            pnbf[w][k * 3 + l] = v - qv;
            feat[w][k][64 + 61 + l] = r[64 + l];   // elements 64..66 -> f[61..63]
        } else {
            feat[w][k][64 + (l - 3)] = v;          // elements 3..66 -> f[0..63]
        }
    }

    // ---- Stage B: h1 = BN1(p_nb @ Wpf1 + b1)  (no activation)
    {
        float wa = Wpf1[l], wb = Wpf1[64 + l], wc = Wpf1[128 + l];
        float bias = bpf1[l];
        float s1 = wsf[S_PF1 + l], t1 = wsf[SH_PF1 + l];
#pragma unroll
        for (int k = 0; k < 16; ++k) {
            float a = pnbf[w][k * 3 + 0] * wa + pnbf[w][k * 3 + 1] * wb +
                      pnbf[w][k * 3 + 2] * wc + bias;
            h1l[w][k][l] = s1 * a + t1;
        }
    }

    // ---- Stage C: h2 = BN2(h1 @ Wpf2 + b2) -> feat[:,0:64]
    {
        float acc[16];
        float bias = bpf2[l];
#pragma unroll
        for (int k = 0; k < 16; ++k) acc[k] = bias;
        for (int c4 = 0; c4 < 16; ++c4) {
            float w0 = Wpf2[(4 * c4 + 0) * 64 + l];
            float w1 = Wpf2[(4 * c4 + 1) * 64 + l];
            float w2 = Wpf2[(4 * c4 + 2) * 64 + l];
            float w3 = Wpf2[(4 * c4 + 3) * 64 + l];
#pragma unroll
            for (int k = 0; k < 16; ++k) {
                const float4 h = *reinterpret_cast<const float4*>(&h1l[w][k][4 * c4]);
                acc[k] += h.x * w0 + h.y * w1 + h.z * w2 + h.w * w3;
            }
        }
        float s2 = wsf[S_PF2 + l], t2 = wsf[SH_PF2 + l];
#pragma unroll
        for (int k = 0; k < 16; ++k) feat[w][k][l] = s2 * acc[k] + t2;
    }

    // ---- Stage D: x1 = BN(elu(p_nb(flat48) . Wc1 + b)) -> xb[0]
    {
        float acc[4];
#pragma unroll
        for (int r = 0; r < 4; ++r) acc[r] = bc1[l + 64 * r];
        for (int tt = 0; tt < 48; ++tt) {
            float pv = pnbf[w][tt];
            const float* wr = Wc1 + tt * 256 + l;
#pragma unroll
            for (int r = 0; r < 4; ++r) acc[r] += pv * wr[64 * r];
        }
#pragma unroll
        for (int r = 0; r < 4; ++r) {
            int o = l + 64 * r;
            float z = acc[r];
            float e = (z > 0.f) ? z : expm1f(z);
            xb[w][0][o] = wsf[S_C1 + o] * e + wsf[SH_C1 + o];
        }
    }

    // ---- Stage E: x2[c][m] = BN(elu(sum_w X[w][c]*Wc2[w][c][m] + b))  xb0->xb1
    {
        float acc[4];
#pragma unroll
        for (int r = 0; r < 4; ++r) acc[r] = bc2[l + 64 * r];
        for (int w16 = 0; w16 < 16; ++w16) {
            const float* wr = Wc2 + w16 * 256;
#pragma unroll
            for (int r = 0; r < 4; ++r) {
                int o = l + 64 * r;
                int c = o >> 4;
                acc[r] += xb[w][0][w16 * 16 + c] * wr[o];
            }
        }
#pragma unroll
        for (int r = 0; r < 4; ++r) {
            int o = l + 64 * r;
            float z = acc[r];
            float e = (z > 0.f) ? z : expm1f(z);
            xb[w][1][o] = wsf[S_C2 + o] * e + wsf[SH_C2 + o];
        }
    }

    // ---- Stage F: x3, same structure, xb1 -> xb0
    {
        float acc[4];
#pragma unroll
        for (int r = 0; r < 4; ++r) acc[r] = bc3[l + 64 * r];
        for (int w16 = 0; w16 < 16; ++w16) {
            const float* wr = Wc3 + w16 * 256;
#pragma unroll
            for (int r = 0; r < 4; ++r) {
                int o = l + 64 * r;
                int c = o >> 4;
                acc[r] += xb[w][1][w16 * 16 + c] * wr[o];
            }
        }
#pragma unroll
        for (int r = 0; r < 4; ++r) {
            int o = l + 64 * r;
            float z = acc[r];
            float e = (z > 0.f) ? z : expm1f(z);
            xb[w][0][o] = wsf[S_C3 + o] * e + wsf[SH_C3 + o];
        }
    }

    // ---- Stage G: feat2[i][c] = sum_j X3[i][j]*feat[j][c]  (kept in regs)
    float f2a[16], f2b[16];
#pragma unroll
    for (int i = 0; i < 16; ++i) { f2a[i] = 0.f; f2b[i] = 0.f; }
    for (int j = 0; j < 16; ++j) {
        float fa = feat[w][j][l];
        float fb = feat[w][j][64 + l];
#pragma unroll
        for (int i = 0; i < 16; ++i) {
            float xv = xb[w][0][i * 16 + j];
            f2a[i] += xv * fa;
            f2b[i] += xv * fb;
        }
    }

    // ---- Stage H: dw[c][m] = sum_j feat2[j][c]*Wdf[j][c][m] -> dwl
    {
        float d00 = 0.f, d01 = 0.f, d10 = 0.f, d11 = 0.f;
#pragma unroll
        for (int j = 0; j < 16; ++j) {
            const float* wr = Wdf + j * 256;
            float2 wlo = *reinterpret_cast<const float2*>(wr + 2 * l);
            float2 whi = *reinterpret_cast<const float2*>(wr + 128 + 2 * l);
            d00 += f2a[j] * wlo.x; d01 += f2a[j] * wlo.y;
            d10 += f2b[j] * whi.x; d11 += f2b[j] * whi.y;
        }
        *reinterpret_cast<float2*>(&dwl[w][2 * l])       = make_float2(d00, d01);
        *reinterpret_cast<float2*>(&dwl[w][128 + 2 * l]) = make_float2(d10, d11);
    }

    // ---- Stage I: out = BNf(elu(dw @ Wpw + bf))
    {
        float o0 = bf[l], o1 = bf[64 + l];
        for (int t4 = 0; t4 < 64; ++t4) {
            float4 dv = *reinterpret_cast<const float4*>(&dwl[w][4 * t4]);
            const float* wr = Wpw + (size_t)(4 * t4) * 128;
            o0 += dv.x * wr[l]           + dv.y * wr[128 + l] +
                  dv.z * wr[256 + l]     + dv.w * wr[384 + l];
            o1 += dv.x * wr[64 + l]      + dv.y * wr[128 + 64 + l] +
                  dv.z * wr[256 + 64 + l]+ dv.w * wr[384 + 64 + l];
        }
        float e0 = (o0 > 0.f) ? o0 : expm1f(o0);
        float e1 = (o1 > 0.f) ? o1 : expm1f(o1);
        float r0 = wsf[S_F + l]      * e0 + wsf[SH_F + l];
        float r1 = wsf[S_F + 64 + l] * e1 + wsf[SH_F + 64 + l];

        float* orow = out + (size_t)ng * 131;
        orow[3 + l]      = r0;
        orow[3 + 64 + l] = r1;
        if (l < 3) orow[l] = (l == 0) ? q0 : ((l == 1) ? q1 : q2);
    }
}

// ---------------------------------------------------------------------------
extern "C" void kernel_launch(void* const* d_in, const int* in_sizes, int n_in,
                              void* d_out, int out_size, void* d_ws, size_t ws_size,
                              hipStream_t stream) {
    const float* inp   = (const float*)d_in[0];
    const float* Wpf1  = (const float*)d_in[1];
    const float* bpf1  = (const float*)d_in[2];
    const float* bnpf1 = (const float*)d_in[3];
    const float* Wpf2  = (const float*)d_in[4];
    const float* bpf2  = (const float*)d_in[5];
    const float* bnpf2 = (const float*)d_in[6];
    const float* Wc1   = (const float*)d_in[7];
    const float* bc1   = (const float*)d_in[8];
    const float* bnc1  = (const float*)d_in[9];
    const float* Wc2   = (const float*)d_in[10];
    const float* bc2   = (const float*)d_in[11];
    const float* bnc2  = (const float*)d_in[12];
    const float* Wc3   = (const float*)d_in[13];
    const float* bc3   = (const float*)d_in[14];
    const float* bnc3  = (const float*)d_in[15];
    const float* Wdf   = (const float*)d_in[16];
    const float* Wpw   = (const float*)d_in[17];
    const float* bf    = (const float*)d_in[18];
    const float* bnf   = (const float*)d_in[19];

    float* wsf  = (float*)d_ws;
    int*   idxw = (int*)((char*)d_ws + 8192);
    float* outp = (float*)d_out;

    hipLaunchKernelGGL(bn_prep, dim3(1), dim3(1024), 0, stream,
                       bnpf1, bnpf2, bnc1, bnc2, bnc3, bnf, wsf);
    hipLaunchKernelGGL(knn_kernel, dim3(256), dim3(64), 0, stream, inp, idxw);
    hipLaunchKernelGGL(pipeline_kernel, dim3(4096), dim3(128), 0, stream,
                       inp, idxw, Wpf1, bpf1, Wpf2, bpf2, Wc1, bc1, Wc2, bc2,
                       Wc3, bc3, Wdf, Wpw, bf, wsf, outp);
}

// Round 2
// 217.708 us; speedup vs baseline: 10.5938x; 10.5938x over previous
//
#include <hip/hip_runtime.h>
#include <math.h>

#define B_    8
#define NIN_  4096
#define P_    1024
#define K_    16
#define F_    64
#define CH_   67      // 3 + F
#define CPF_  64
#define CIN_  128
#define C_    128

// ---- ws layout: BN scale/shift floats [0..2048), pts float4 @8192B, idx after
#define S_PF1  0
#define SH_PF1 64
#define S_PF2  128
#define SH_PF2 192
#define S_C1   256
#define SH_C1  512
#define S_C2   768
#define SH_C2  1024
#define S_C3   1280
#define SH_C3  1536
#define S_F    1792
#define SH_F   1920

#define WS_PTS_OFF  8192
#define WS_IDX_OFF  (8192 + B_ * NIN_ * 16)

// ---------------------------------------------------------------------------
// Kernel 0: fold BN params (stacked [g,b,m,v] rows) into scale/shift
// ---------------------------------------------------------------------------
__global__ void bn_prep(const float* __restrict__ bn_pf1, const float* __restrict__ bn_pf2,
                        const float* __restrict__ bn_c1,  const float* __restrict__ bn_c2,
                        const float* __restrict__ bn_c3,  const float* __restrict__ bn_f,
                        float* __restrict__ wsf) {
    int t = threadIdx.x;
    const float* src; int nch, c, so, sho;
    if (t < 64)       { src = bn_pf1; nch = 64;  c = t;        so = S_PF1; sho = SH_PF1; }
    else if (t < 128) { src = bn_pf2; nch = 64;  c = t - 64;   so = S_PF2; sho = SH_PF2; }
    else if (t < 384) { src = bn_c1;  nch = 256; c = t - 128;  so = S_C1;  sho = SH_C1; }
    else if (t < 640) { src = bn_c2;  nch = 256; c = t - 384;  so = S_C2;  sho = SH_C2; }
    else if (t < 896) { src = bn_c3;  nch = 256; c = t - 640;  so = S_C3;  sho = SH_C3; }
    else              { src = bn_f;   nch = 128; c = t - 896;  so = S_F;   sho = SH_F;  }
    float g = src[c], b = src[nch + c], m = src[2 * nch + c], v = src[3 * nch + c];
    float s = g * rsqrtf(v + 1e-3f);
    wsf[so + c]  = s;
    wsf[sho + c] = b - m * s;
}

// ---------------------------------------------------------------------------
// Kernel 0b: pack xyz + |p|^2 into float4 (pp bitwise-identical to reference)
// ---------------------------------------------------------------------------
__global__ __launch_bounds__(256) void pack_pts(const float* __restrict__ inp,
                                                float4* __restrict__ pts) {
    int i = blockIdx.x * 256 + threadIdx.x;
    if (i < B_ * NIN_) {
        const float* r = inp + (size_t)i * CH_;
        float x = r[0], y = r[1], z = r[2];
        float pp = __fadd_rn(__fadd_rn(__fmul_rn(x, x), __fmul_rn(y, y)),
                             __fmul_rn(z, z));
        pts[i] = make_float4(x, y, z, pp);
    }
}

// ---------------------------------------------------------------------------
// Kernel 1: exact KNN. One WAVE per query; sorted top-32 lives across lanes
// 0..31 in registers (lane s = s-th smallest). Wave-parallel shfl insertion,
// wave-uniform scalar control flow, zero LDS.
// d2 bitwise-identical to reference: d2 = (qq + pp) - (2*e), no FMA.
// ---------------------------------------------------------------------------
__global__ __launch_bounds__(256) void knn_kernel(const float4* __restrict__ pts,
                                                  int* __restrict__ idxo) {
    const int wid  = (blockIdx.x << 2) | (threadIdx.x >> 6);  // query id 0..8191
    const int lane = threadIdx.x & 63;
    const int b    = wid >> 10;
    const int qi   = wid & 1023;
    const float4* bp = pts + ((size_t)b << 12);

    const float4 q = bp[qi];
    const float qq = q.w;

    float bd = 1e30f;   // lane s: s-th smallest distance so far
    int   bi = 0;
    float kth = 1e30f;  // current 32nd smallest (uniform)

    for (int j0 = 0; j0 < NIN_; j0 += 64) {
        float4 p = bp[j0 + lane];
        float e  = __fadd_rn(__fadd_rn(__fmul_rn(q.x, p.x), __fmul_rn(q.y, p.y)),
                             __fmul_rn(q.z, p.z));
        float d2 = __fsub_rn(__fadd_rn(qq, p.w), __fmul_rn(2.0f, e));

        unsigned long long m = __ballot(d2 < kth);
        while (m) {
            int c = __builtin_ctzll(m);
            m &= m - 1;
            float dc = __shfl(d2, c);          // uniform broadcast
            if (dc < kth) {                    // uniform branch
                int   ic    = j0 + c;
                float prev  = __shfl_up(bd, 1);
                int   previ = __shfl_up(bi, 1);
                bool  shift = (bd > dc);       // strict: ties keep lower index first
                bool  ins   = shift && ((lane == 0) || (prev <= dc));
                if (shift) { bd = prev; bi = previ; }
                if (ins)   { bd = dc;   bi = ic;    }
                kth = __shfl(bd, 31);
            }
        }
    }

    // dilated take: ranks 0,2,4,...,30 -> 16 neighbor indices
    if (lane < 32 && !(lane & 1)) {
        idxo[((size_t)wid << 4) | (lane >> 1)] = bi;
    }
}

// ---------------------------------------------------------------------------
// Kernel 2: full per-point pipeline. One wave (64 lanes) per point; 2 points
// per 128-thread block. No __syncthreads: each wave owns a private LDS slice
// and relies on in-order per-wave LDS ops.
// ---------------------------------------------------------------------------
__global__ __launch_bounds__(128) void pipeline_kernel(
    const float* __restrict__ inp, const int* __restrict__ idx,
    const float* __restrict__ Wpf1, const float* __restrict__ bpf1,
    const float* __restrict__ Wpf2, const float* __restrict__ bpf2,
    const float* __restrict__ Wc1,  const float* __restrict__ bc1,
    const float* __restrict__ Wc2,  const float* __restrict__ bc2,
    const float* __restrict__ Wc3,  const float* __restrict__ bc3,
    const float* __restrict__ Wdf,  const float* __restrict__ Wpw,
    const float* __restrict__ bf,   const float* __restrict__ wsf,
    float* __restrict__ out) {

    __shared__ float pnbf[2][48];        // p_nb flat [k*3+d]
    __shared__ float h1l[2][16][64];     // h after pf1+BN
    __shared__ float feat[2][16][128];   // [h2 | f_nb]
    __shared__ float xb[2][2][256];      // ping-pong x buffers
    __shared__ float dwl[2][256];        // dw flat

    const int w  = threadIdx.x >> 6;
    const int l  = threadIdx.x & 63;
    const int ng = blockIdx.x * 2 + w;   // global point id (b*1024+n)
    const int b  = ng >> 10;
    const int n  = ng & 1023;
    const float* brow = inp + (size_t)b * NIN_ * CH_;
    const int* ip = idx + (size_t)ng * K_;

    const float q0 = brow[(size_t)n * CH_ + 0];
    const float q1 = brow[(size_t)n * CH_ + 1];
    const float q2 = brow[(size_t)n * CH_ + 2];

    // ---- Stage A: gather neighbor rows -> pnbf (xyz - q) and feat[:,64:128]
    for (int k = 0; k < 16; ++k) {
        const float* r = brow + (size_t)ip[k] * CH_;
        float v = r[l];
        if (l < 3) {
            float qv = (l == 0) ? q0 : ((l == 1) ? q1 : q2);
            pnbf[w][k * 3 + l] = v - qv;
            feat[w][k][64 + 61 + l] = r[64 + l];   // elements 64..66 -> f[61..63]
        } else {
            feat[w][k][64 + (l - 3)] = v;          // elements 3..66 -> f[0..63]
        }
    }

    // ---- Stage B: h1 = BN1(p_nb @ Wpf1 + b1)  (no activation)
    {
        float wa = Wpf1[l], wb = Wpf1[64 + l], wc = Wpf1[128 + l];
        float bias = bpf1[l];
        float s1 = wsf[S_PF1 + l], t1 = wsf[SH_PF1 + l];
#pragma unroll
        for (int k = 0; k < 16; ++k) {
            float a = pnbf[w][k * 3 + 0] * wa + pnbf[w][k * 3 + 1] * wb +
                      pnbf[w][k * 3 + 2] * wc + bias;
            h1l[w][k][l] = s1 * a + t1;
        }
    }

    // ---- Stage C: h2 = BN2(h1 @ Wpf2 + b2) -> feat[:,0:64]
    {
        float acc[16];
        float bias = bpf2[l];
#pragma unroll
        for (int k = 0; k < 16; ++k) acc[k] = bias;
        for (int c4 = 0; c4 < 16; ++c4) {
            float w0 = Wpf2[(4 * c4 + 0) * 64 + l];
            float w1 = Wpf2[(4 * c4 + 1) * 64 + l];
            float w2 = Wpf2[(4 * c4 + 2) * 64 + l];
            float w3 = Wpf2[(4 * c4 + 3) * 64 + l];
#pragma unroll
            for (int k = 0; k < 16; ++k) {
                const float4 h = *reinterpret_cast<const float4*>(&h1l[w][k][4 * c4]);
                acc[k] += h.x * w0 + h.y * w1 + h.z * w2 + h.w * w3;
            }
        }
        float s2 = wsf[S_PF2 + l], t2 = wsf[SH_PF2 + l];
#pragma unroll
        for (int k = 0; k < 16; ++k) feat[w][k][l] = s2 * acc[k] + t2;
    }

    // ---- Stage D: x1 = BN(elu(p_nb(flat48) . Wc1 + b)) -> xb[0]
    {
        float acc[4];
#pragma unroll
        for (int r = 0; r < 4; ++r) acc[r] = bc1[l + 64 * r];
        for (int tt = 0; tt < 48; ++tt) {
            float pv = pnbf[w][tt];
            const float* wr = Wc1 + tt * 256 + l;
#pragma unroll
            for (int r = 0; r < 4; ++r) acc[r] += pv * wr[64 * r];
        }
#pragma unroll
        for (int r = 0; r < 4; ++r) {
            int o = l + 64 * r;
            float z = acc[r];
            float e = (z > 0.f) ? z : expm1f(z);
            xb[w][0][o] = wsf[S_C1 + o] * e + wsf[SH_C1 + o];
        }
    }

    // ---- Stage E: x2[c][m] = BN(elu(sum_w X[w][c]*Wc2[w][c][m] + b))  xb0->xb1
    {
        float acc[4];
#pragma unroll
        for (int r = 0; r < 4; ++r) acc[r] = bc2[l + 64 * r];
        for (int w16 = 0; w16 < 16; ++w16) {
            const float* wr = Wc2 + w16 * 256;
#pragma unroll
            for (int r = 0; r < 4; ++r) {
                int o = l + 64 * r;
                int c = o >> 4;
                acc[r] += xb[w][0][w16 * 16 + c] * wr[o];
            }
        }
#pragma unroll
        for (int r = 0; r < 4; ++r) {
            int o = l + 64 * r;
            float z = acc[r];
            float e = (z > 0.f) ? z : expm1f(z);
            xb[w][1][o] = wsf[S_C2 + o] * e + wsf[SH_C2 + o];
        }
    }

    // ---- Stage F: x3, same structure, xb1 -> xb0
    {
        float acc[4];
#pragma unroll
        for (int r = 0; r < 4; ++r) acc[r] = bc3[l + 64 * r];
        for (int w16 = 0; w16 < 16; ++w16) {
            const float* wr = Wc3 + w16 * 256;
#pragma unroll
            for (int r = 0; r < 4; ++r) {
                int o = l + 64 * r;
                int c = o >> 4;
                acc[r] += xb[w][1][w16 * 16 + c] * wr[o];
            }
        }
#pragma unroll
        for (int r = 0; r < 4; ++r) {
            int o = l + 64 * r;
            float z = acc[r];
            float e = (z > 0.f) ? z : expm1f(z);
            xb[w][0][o] = wsf[S_C3 + o] * e + wsf[SH_C3 + o];
        }
    }

    // ---- Stage G: feat2[i][c] = sum_j X3[i][j]*feat[j][c]  (kept in regs)
    float f2a[16], f2b[16];
#pragma unroll
    for (int i = 0; i < 16; ++i) { f2a[i] = 0.f; f2b[i] = 0.f; }
    for (int j = 0; j < 16; ++j) {
        float fa = feat[w][j][l];
        float fb = feat[w][j][64 + l];
#pragma unroll
        for (int i = 0; i < 16; ++i) {
            float xv = xb[w][0][i * 16 + j];
            f2a[i] += xv * fa;
            f2b[i] += xv * fb;
        }
    }

    // ---- Stage H: dw[c][m] = sum_j feat2[j][c]*Wdf[j][c][m] -> dwl
    {
        float d00 = 0.f, d01 = 0.f, d10 = 0.f, d11 = 0.f;
#pragma unroll
        for (int j = 0; j < 16; ++j) {
            const float* wr = Wdf + j * 256;
            float2 wlo = *reinterpret_cast<const float2*>(wr + 2 * l);
            float2 whi = *reinterpret_cast<const float2*>(wr + 128 + 2 * l);
            d00 += f2a[j] * wlo.x; d01 += f2a[j] * wlo.y;
            d10 += f2b[j] * whi.x; d11 += f2b[j] * whi.y;
        }
        *reinterpret_cast<float2*>(&dwl[w][2 * l])       = make_float2(d00, d01);
        *reinterpret_cast<float2*>(&dwl[w][128 + 2 * l]) = make_float2(d10, d11);
    }

    // ---- Stage I: out = BNf(elu(dw @ Wpw + bf))
    {
        float o0 = bf[l], o1 = bf[64 + l];
        for (int t4 = 0; t4 < 64; ++t4) {
            float4 dv = *reinterpret_cast<const float4*>(&dwl[w][4 * t4]);
            const float* wr = Wpw + (size_t)(4 * t4) * 128;
            o0 += dv.x * wr[l]           + dv.y * wr[128 + l] +
                  dv.z * wr[256 + l]     + dv.w * wr[384 + l];
            o1 += dv.x * wr[64 + l]      + dv.y * wr[128 + 64 + l] +
                  dv.z * wr[256 + 64 + l]+ dv.w * wr[384 + 64 + l];
        }
        float e0 = (o0 > 0.f) ? o0 : expm1f(o0);
        float e1 = (o1 > 0.f) ? o1 : expm1f(o1);
        float r0 = wsf[S_F + l]      * e0 + wsf[SH_F + l];
        float r1 = wsf[S_F + 64 + l] * e1 + wsf[SH_F + 64 + l];

        float* orow = out + (size_t)ng * 131;
        orow[3 + l]      = r0;
        orow[3 + 64 + l] = r1;
        if (l < 3) orow[l] = (l == 0) ? q0 : ((l == 1) ? q1 : q2);
    }
}

// ---------------------------------------------------------------------------
extern "C" void kernel_launch(void* const* d_in, const int* in_sizes, int n_in,
                              void* d_out, int out_size, void* d_ws, size_t ws_size,
                              hipStream_t stream) {
    const float* inp   = (const float*)d_in[0];
    const float* Wpf1  = (const float*)d_in[1];
    const float* bpf1  = (const float*)d_in[2];
    const float* bnpf1 = (const float*)d_in[3];
    const float* Wpf2  = (const float*)d_in[4];
    const float* bpf2  = (const float*)d_in[5];
    const float* bnpf2 = (const float*)d_in[6];
    const float* Wc1   = (const float*)d_in[7];
    const float* bc1   = (const float*)d_in[8];
    const float* bnc1  = (const float*)d_in[9];
    const float* Wc2   = (const float*)d_in[10];
    const float* bc2   = (const float*)d_in[11];
    const float* bnc2  = (const float*)d_in[12];
    const float* Wc3   = (const float*)d_in[13];
    const float* bc3   = (const float*)d_in[14];
    const float* bnc3  = (const float*)d_in[15];
    const float* Wdf   = (const float*)d_in[16];
    const float* Wpw   = (const float*)d_in[17];
    const float* bf    = (const float*)d_in[18];
    const float* bnf   = (const float*)d_in[19];

    float*  wsf  = (float*)d_ws;
    float4* pts  = (float4*)((char*)d_ws + WS_PTS_OFF);
    int*    idxw = (int*)((char*)d_ws + WS_IDX_OFF);
    float*  outp = (float*)d_out;

    hipLaunchKernelGGL(bn_prep, dim3(1), dim3(1024), 0, stream,
                       bnpf1, bnpf2, bnc1, bnc2, bnc3, bnf, wsf);
    hipLaunchKernelGGL(pack_pts, dim3((B_ * NIN_ + 255) / 256), dim3(256), 0, stream,
                       inp, pts);
    hipLaunchKernelGGL(knn_kernel, dim3((B_ * P_) / 4), dim3(256), 0, stream,
                       pts, idxw);
    hipLaunchKernelGGL(pipeline_kernel, dim3(4096), dim3(128), 0, stream,
                       inp, idxw, Wpf1, bpf1, Wpf2, bpf2, Wc1, bc1, Wc2, bc2,
                       Wc3, bc3, Wdf, Wpw, bf, wsf, outp);
}

// Round 3
// 181.165 us; speedup vs baseline: 12.7307x; 1.2017x over previous
//
#include <hip/hip_runtime.h>
#include <math.h>

#define B_    8
#define NIN_  4096
#define P_    1024
#define K_    16
#define F_    64
#define CH_   67      // 3 + F
#define CPF_  64
#define CIN_  128
#define C_    128

// ---- ws float-offset layout ----
#define S_PF1  0
#define SH_PF1 64
#define S_PF2  128
#define SH_PF2 192
#define S_C1   256
#define SH_C1  512
#define S_C2   768
#define SH_C2  1024
#define S_C3   1280
#define SH_C3  1536
#define S_F    1792
#define SH_F   1920
#define M_OFF  2048     // fused pf matrix 3x64
#define C0_OFF 2240     // fused pf bias 64

// byte offsets in ws
#define WS_PTS_OFF  16384
#define WS_IDX_OFF  (WS_PTS_OFF + B_ * NIN_ * 16)          // 540672
#define WS_DWL_OFF  (WS_IDX_OFF + B_ * P_ * K_ * 4)        // 1064960

__device__ __forceinline__ float rlf(float x, int l) {
    return __int_as_float(__builtin_amdgcn_readlane(__float_as_int(x), l));
}
__device__ __forceinline__ float eluf(float z) {
    return z > 0.f ? z : expm1f(z);
}

// ---------------------------------------------------------------------------
// Kernel 0: fold BN params into scale/shift; then collapse pf1+pf2 into a
// single 3->64 affine (M, c0) since there is no nonlinearity between them.
// ---------------------------------------------------------------------------
__global__ void bn_prep(const float* __restrict__ bn_pf1, const float* __restrict__ bn_pf2,
                        const float* __restrict__ bn_c1,  const float* __restrict__ bn_c2,
                        const float* __restrict__ bn_c3,  const float* __restrict__ bn_f,
                        const float* __restrict__ Wpf1,   const float* __restrict__ bpf1,
                        const float* __restrict__ Wpf2,   const float* __restrict__ bpf2,
                        float* __restrict__ wsf) {
    int t = threadIdx.x;
    {
        const float* src; int nch, c, so, sho;
        if (t < 64)       { src = bn_pf1; nch = 64;  c = t;        so = S_PF1; sho = SH_PF1; }
        else if (t < 128) { src = bn_pf2; nch = 64;  c = t - 64;   so = S_PF2; sho = SH_PF2; }
        else if (t < 384) { src = bn_c1;  nch = 256; c = t - 128;  so = S_C1;  sho = SH_C1; }
        else if (t < 640) { src = bn_c2;  nch = 256; c = t - 384;  so = S_C2;  sho = SH_C2; }
        else if (t < 896) { src = bn_c3;  nch = 256; c = t - 640;  so = S_C3;  sho = SH_C3; }
        else              { src = bn_f;   nch = 128; c = t - 896;  so = S_F;   sho = SH_F;  }
        float g = src[c], b = src[nch + c], m = src[2 * nch + c], v = src[3 * nch + c];
        float s = g * rsqrtf(v + 1e-3f);
        wsf[so + c]  = s;
        wsf[sho + c] = b - m * s;
    }
    __syncthreads();
    if (t < 64) {
        int o = t;
        float s2 = wsf[S_PF2 + o], t2 = wsf[SH_PF2 + o];
        float m0 = 0.f, m1 = 0.f, m2 = 0.f, cc = 0.f;
        for (int c = 0; c < 64; ++c) {
            float s1 = wsf[S_PF1 + c], t1 = wsf[SH_PF1 + c];
            float d1 = s1 * bpf1[c] + t1;
            float w2 = Wpf2[c * 64 + o];
            m0 += Wpf1[0 * 64 + c] * s1 * w2;
            m1 += Wpf1[1 * 64 + c] * s1 * w2;
            m2 += Wpf1[2 * 64 + c] * s1 * w2;
            cc += d1 * w2;
        }
        wsf[M_OFF + 0 * 64 + o] = m0 * s2;
        wsf[M_OFF + 1 * 64 + o] = m1 * s2;
        wsf[M_OFF + 2 * 64 + o] = m2 * s2;
        wsf[C0_OFF + o]         = cc * s2 + bpf2[o] * s2 + t2;
    }
}

// ---------------------------------------------------------------------------
// Kernel 0b: pack xyz + |p|^2 into float4 (pp bitwise-identical to reference)
// ---------------------------------------------------------------------------
__global__ __launch_bounds__(256) void pack_pts(const float* __restrict__ inp,
                                                float4* __restrict__ pts) {
    int i = blockIdx.x * 256 + threadIdx.x;
    if (i < B_ * NIN_) {
        const float* r = inp + (size_t)i * CH_;
        float x = r[0], y = r[1], z = r[2];
        float pp = __fadd_rn(__fadd_rn(__fmul_rn(x, x), __fmul_rn(y, y)),
                             __fmul_rn(z, z));
        pts[i] = make_float4(x, y, z, pp);
    }
}

// ---------------------------------------------------------------------------
// Kernel 1: exact KNN. One wave per query; sorted top-32 across lanes 0..31.
// First 64 candidates via cross-lane bitonic sort (keyed (d2, idx) asc);
// remaining via wave-parallel insertion (2 ds ops/insert, readlane for
// broadcasts). d2 bitwise-identical: d2 = (qq + pp) - (2*e), no FMA.
// ---------------------------------------------------------------------------
__global__ __launch_bounds__(256) void knn_kernel(const float4* __restrict__ pts,
                                                  int* __restrict__ idxo) {
    const int wid  = (blockIdx.x << 2) | (threadIdx.x >> 6);  // query id 0..8191
    const int lane = threadIdx.x & 63;
    const float4* bp = pts + ((size_t)(wid >> 10) << 12);
    const int qi = wid & 1023;

    const float4 q = bp[qi];
    const float qq = q.w;

    // ---- group 0: bitonic sort 64 candidates by (d2, idx) ascending
    float4 p = bp[lane];
    float d;
    {
        float e = __fadd_rn(__fadd_rn(__fmul_rn(q.x, p.x), __fmul_rn(q.y, p.y)),
                            __fmul_rn(q.z, p.z));
        d = __fsub_rn(__fadd_rn(qq, p.w), __fmul_rn(2.0f, e));
    }
    int ii = lane;
#pragma unroll
    for (int k = 2; k <= 64; k <<= 1) {
#pragma unroll
        for (int j = k >> 1; j > 0; j >>= 1) {
            float od = __shfl_xor(d, j);
            int   oi = __shfl_xor(ii, j);
            bool keepmin = (((lane & k) == 0) == ((lane & j) == 0));
            bool ol = (od < d) || (od == d && oi < ii);
            bool take = keepmin ? ol : !ol;
            if (take) { d = od; ii = oi; }
        }
    }
    float bd = d;      // lane s (<32): s-th smallest
    int   bi = ii;
    float kth = rlf(bd, 31);

    float4 pn = bp[64 + lane];
    for (int j0 = 64; j0 < NIN_; j0 += 64) {
        p = pn;
        if (j0 + 64 < NIN_) pn = bp[j0 + 64 + lane];
        float e  = __fadd_rn(__fadd_rn(__fmul_rn(q.x, p.x), __fmul_rn(q.y, p.y)),
                             __fmul_rn(q.z, p.z));
        float d2 = __fsub_rn(__fadd_rn(qq, p.w), __fmul_rn(2.0f, e));

        unsigned long long m = __ballot(d2 < kth);
        while (m) {
            int c = __builtin_ctzll(m);
            m &= m - 1;
            float dc = rlf(d2, c);          // uniform (SGPR) broadcast
            if (dc < kth) {                 // uniform branch
                int   ic    = j0 + c;
                float prev  = __shfl_up(bd, 1);
                int   previ = __shfl_up(bi, 1);
                bool  shift = (bd > dc);    // strict: ties keep lower index first
                bool  ins   = shift && ((lane == 0) || (prev <= dc));
                if (shift) { bd = prev; bi = previ; }
                if (ins)   { bd = dc;   bi = ic;    }
                kth = rlf(bd, 31);
            }
        }
    }

    if (lane < 32 && !(lane & 1)) {
        idxo[((size_t)wid << 4) | (lane >> 1)] = bi;
    }
}

// ---------------------------------------------------------------------------
// Kernel 2: stages A..H (all but the final 256->128 pointwise layer).
// One wave per point, 4 waves/block, no barriers. feat (h2|f_nb) and X3 live
// in registers; cross-lane broadcasts via v_readlane (VALU, not LDS pipe).
// Writes dw rows [8192][256] to ws for the GEMM kernel.
// ---------------------------------------------------------------------------
__global__ __launch_bounds__(256) void p1_kernel(
    const float* __restrict__ inp, const int* __restrict__ idx,
    const float* __restrict__ Wc1,  const float* __restrict__ bc1,
    const float* __restrict__ Wc2,  const float* __restrict__ bc2,
    const float* __restrict__ Wc3,  const float* __restrict__ bc3,
    const float* __restrict__ Wdf,  const float* __restrict__ wsf,
    float* __restrict__ dwl, float* __restrict__ out) {

    __shared__ float pnb[4][64];     // p_nb flat (48 used)
    __shared__ float xA[4][256];
    __shared__ float xB[4][256];

    const int w  = threadIdx.x >> 6;
    const int l  = threadIdx.x & 63;
    const int ng = blockIdx.x * 4 + w;       // global point id
    const int b  = ng >> 10;
    const int n  = ng & 1023;
    const float* brow = inp + (size_t)b * NIN_ * CH_;
    const int* ip = idx + (size_t)ng * K_;

    const float q0 = brow[(size_t)n * CH_ + 0];
    const float q1 = brow[(size_t)n * CH_ + 1];
    const float q2 = brow[(size_t)n * CH_ + 2];

    int nb[16];
#pragma unroll
    for (int k = 0; k < 16; ++k) nb[k] = ip[k];

    // ---- Stage A+B': gather + fused pf (h2 = pnb @ M + c0)
    const float Mw0 = wsf[M_OFF + l];
    const float Mw1 = wsf[M_OFF + 64 + l];
    const float Mw2 = wsf[M_OFF + 128 + l];
    const float cc0 = wsf[C0_OFF + l];
    float h2[16], fnb[16];
#pragma unroll
    for (int k = 0; k < 16; ++k) {
        const float* r = brow + (size_t)nb[k] * CH_;
        float v  = r[l];                      // lanes 0..2 -> xyz
        fnb[k]   = r[3 + l];                  // channels 0..63
        float qv = (l == 0) ? q0 : ((l == 1) ? q1 : q2);
        float pd = v - qv;
        if (l < 3) pnb[w][k * 3 + l] = pd;
        float s0 = rlf(pd, 0), s1 = rlf(pd, 1), s2 = rlf(pd, 2);
        h2[k] = fmaf(s0, Mw0, fmaf(s1, Mw1, fmaf(s2, Mw2, cc0)));
    }

    // ---- Stage D: x1[o] = BN(elu(pnb48 . Wc1 + bc1)),  o = 4l+r
    {
        float4 acc = *reinterpret_cast<const float4*>(bc1 + 4 * l);
#pragma unroll
        for (int t12 = 0; t12 < 12; ++t12) {
            float4 pv = *reinterpret_cast<const float4*>(&pnb[w][t12 * 4]);
            const float* wb = Wc1 + (size_t)(t12 * 4) * 256 + 4 * l;
            float4 w0 = *reinterpret_cast<const float4*>(wb);
            float4 w1 = *reinterpret_cast<const float4*>(wb + 256);
            float4 w2 = *reinterpret_cast<const float4*>(wb + 512);
            float4 w3 = *reinterpret_cast<const float4*>(wb + 768);
            acc.x += pv.x * w0.x + pv.y * w1.x + pv.z * w2.x + pv.w * w3.x;
            acc.y += pv.x * w0.y + pv.y * w1.y + pv.z * w2.y + pv.w * w3.y;
            acc.z += pv.x * w0.z + pv.y * w1.z + pv.z * w2.z + pv.w * w3.z;
            acc.w += pv.x * w0.w + pv.y * w1.w + pv.z * w2.w + pv.w * w3.w;
        }
        float4 sc = *reinterpret_cast<const float4*>(wsf + S_C1 + 4 * l);
        float4 sh = *reinterpret_cast<const float4*>(wsf + SH_C1 + 4 * l);
        float4 r;
        r.x = sc.x * eluf(acc.x) + sh.x;
        r.y = sc.y * eluf(acc.y) + sh.y;
        r.z = sc.z * eluf(acc.z) + sh.z;
        r.w = sc.w * eluf(acc.w) + sh.w;
        *reinterpret_cast<float4*>(&xA[w][4 * l]) = r;
    }

    // ---- Stage E: x2[o] = BN(elu(sum_w x1[w][c]*Wc2[w][o])),  c = l>>2
    {
        float4 acc = *reinterpret_cast<const float4*>(bc2 + 4 * l);
        const int csel = l >> 2;
#pragma unroll
        for (int w16 = 0; w16 < 16; ++w16) {
            float xs = xA[w][w16 * 16 + csel];
            float4 w4 = *reinterpret_cast<const float4*>(Wc2 + (size_t)w16 * 256 + 4 * l);
            acc.x += xs * w4.x; acc.y += xs * w4.y;
            acc.z += xs * w4.z; acc.w += xs * w4.w;
        }
        float4 sc = *reinterpret_cast<const float4*>(wsf + S_C2 + 4 * l);
        float4 sh = *reinterpret_cast<const float4*>(wsf + SH_C2 + 4 * l);
        float4 r;
        r.x = sc.x * eluf(acc.x) + sh.x;
        r.y = sc.y * eluf(acc.y) + sh.y;
        r.z = sc.z * eluf(acc.z) + sh.z;
        r.w = sc.w * eluf(acc.w) + sh.w;
        *reinterpret_cast<float4*>(&xB[w][4 * l]) = r;
    }

    // ---- Stage F: x3 (kept in registers, o = 4l..4l+3)
    float x3r[4];
    {
        float4 acc = *reinterpret_cast<const float4*>(bc3 + 4 * l);
        const int csel = l >> 2;
#pragma unroll
        for (int w16 = 0; w16 < 16; ++w16) {
            float xs = xB[w][w16 * 16 + csel];
            float4 w4 = *reinterpret_cast<const float4*>(Wc3 + (size_t)w16 * 256 + 4 * l);
            acc.x += xs * w4.x; acc.y += xs * w4.y;
            acc.z += xs * w4.z; acc.w += xs * w4.w;
        }
        float4 sc = *reinterpret_cast<const float4*>(wsf + S_C3 + 4 * l);
        float4 sh = *reinterpret_cast<const float4*>(wsf + SH_C3 + 4 * l);
        x3r[0] = sc.x * eluf(acc.x) + sh.x;
        x3r[1] = sc.y * eluf(acc.y) + sh.y;
        x3r[2] = sc.z * eluf(acc.z) + sh.z;
        x3r[3] = sc.w * eluf(acc.w) + sh.w;
    }

    // ---- Stage G+H fused: feat2 row i -> immediately folded into dw
    //   feat2[i][c] = sum_j X3[i][j]*feat[j][c];  X3[i][j] via readlane
    //   dw[c*2+m]   = sum_i feat2[i][c]*Wdf[i][c][m]
    float d00 = 0.f, d01 = 0.f, d10 = 0.f, d11 = 0.f;
#pragma unroll
    for (int i = 0; i < 16; ++i) {
        float fa = 0.f, fb = 0.f;
#pragma unroll
        for (int j = 0; j < 16; ++j) {
            const int o = i * 16 + j;
            float xv = rlf(x3r[o & 3], o >> 2);
            fa += xv * h2[j];
            fb += xv * fnb[j];
        }
        const float* wr = Wdf + (size_t)i * 256;
        float2 wlo = *reinterpret_cast<const float2*>(wr + 2 * l);
        float2 whi = *reinterpret_cast<const float2*>(wr + 128 + 2 * l);
        d00 += fa * wlo.x; d01 += fa * wlo.y;
        d10 += fb * whi.x; d11 += fb * whi.y;
    }
    float* drow = dwl + (size_t)ng * 256;
    *reinterpret_cast<float2*>(drow + 2 * l)       = make_float2(d00, d01);
    *reinterpret_cast<float2*>(drow + 128 + 2 * l) = make_float2(d10, d11);

    if (l < 3) out[(size_t)ng * 131 + l] = (l == 0) ? q0 : ((l == 1) ? q1 : q2);
}

// ---------------------------------------------------------------------------
// Kernel 3: final pointwise layer as a tiled f32 GEMM:
//   out[m][n] = BNf(elu(dw[m][:] @ Wpw[:][n] + bf[n])),  M=8192 K=256 N=128.
// Mtile=32 per block (A tile in LDS), thread tile 4m x 4n.
// ---------------------------------------------------------------------------
__global__ __launch_bounds__(256) void pw_kernel(const float* __restrict__ dwl,
                                                 const float* __restrict__ Wpw,
                                                 const float* __restrict__ bf,
                                                 const float* __restrict__ wsf,
                                                 float* __restrict__ out) {
    __shared__ float As[32][256];
    const int tid = threadIdx.x;
    const int m0  = blockIdx.x * 32;

#pragma unroll
    for (int i = 0; i < 8; ++i) {
        int fi  = i * 1024 + tid * 4;
        int row = fi >> 8, col = fi & 255;
        *reinterpret_cast<float4*>(&As[row][col]) =
            *reinterpret_cast<const float4*>(dwl + (size_t)(m0 + row) * 256 + col);
    }
    __syncthreads();

    const int mq = tid >> 5;          // 8 m-quads
    const int nq = tid & 31;          // 32 n-quads
    float acc[4][4];
#pragma unroll
    for (int mi = 0; mi < 4; ++mi)
#pragma unroll
        for (int ni = 0; ni < 4; ++ni) acc[mi][ni] = 0.f;

#pragma unroll 4
    for (int k4 = 0; k4 < 64; ++k4) {
        float4 a[4], bw[4];
#pragma unroll
        for (int mi = 0; mi < 4; ++mi)
            a[mi] = *reinterpret_cast<const float4*>(&As[mq * 4 + mi][k4 * 4]);
#pragma unroll
        for (int ki = 0; ki < 4; ++ki)
            bw[ki] = *reinterpret_cast<const float4*>(Wpw + (size_t)(k4 * 4 + ki) * 128 + nq * 4);
#pragma unroll
        for (int mi = 0; mi < 4; ++mi) {
            const float4 am = a[mi];
            acc[mi][0] += am.x * bw[0].x + am.y * bw[1].x + am.z * bw[2].x + am.w * bw[3].x;
            acc[mi][1] += am.x * bw[0].y + am.y * bw[1].y + am.z * bw[2].y + am.w * bw[3].y;
            acc[mi][2] += am.x * bw[0].z + am.y * bw[1].z + am.z * bw[2].z + am.w * bw[3].z;
            acc[mi][3] += am.x * bw[0].w + am.y * bw[1].w + am.z * bw[2].w + am.w * bw[3].w;
        }
    }

    float4 b4  = *reinterpret_cast<const float4*>(bf + nq * 4);
    float4 sc4 = *reinterpret_cast<const float4*>(wsf + S_F + nq * 4);
    float4 sh4 = *reinterpret_cast<const float4*>(wsf + SH_F + nq * 4);
#pragma unroll
    for (int mi = 0; mi < 4; ++mi) {
        const int m = m0 + mq * 4 + mi;
        float* orow = out + (size_t)m * 131 + 3 + nq * 4;
        orow[0] = sc4.x * eluf(acc[mi][0] + b4.x) + sh4.x;
        orow[1] = sc4.y * eluf(acc[mi][1] + b4.y) + sh4.y;
        orow[2] = sc4.z * eluf(acc[mi][2] + b4.z) + sh4.z;
        orow[3] = sc4.w * eluf(acc[mi][3] + b4.w) + sh4.w;
    }
}

// ---------------------------------------------------------------------------
extern "C" void kernel_launch(void* const* d_in, const int* in_sizes, int n_in,
                              void* d_out, int out_size, void* d_ws, size_t ws_size,
                              hipStream_t stream) {
    const float* inp   = (const float*)d_in[0];
    const float* Wpf1  = (const float*)d_in[1];
    const float* bpf1  = (const float*)d_in[2];
    const float* bnpf1 = (const float*)d_in[3];
    const float* Wpf2  = (const float*)d_in[4];
    const float* bpf2  = (const float*)d_in[5];
    const float* bnpf2 = (const float*)d_in[6];
    const float* Wc1   = (const float*)d_in[7];
    const float* bc1   = (const float*)d_in[8];
    const float* bnc1  = (const float*)d_in[9];
    const float* Wc2   = (const float*)d_in[10];
    const float* bc2   = (const float*)d_in[11];
    const float* bnc2  = (const float*)d_in[12];
    const float* Wc3   = (const float*)d_in[13];
    const float* bc3   = (const float*)d_in[14];
    const float* bnc3  = (const float*)d_in[15];
    const float* Wdf   = (const float*)d_in[16];
    const float* Wpw   = (const float*)d_in[17];
    const float* bf    = (const float*)d_in[18];
    const float* bnf   = (const float*)d_in[19];

    float*  wsf  = (float*)d_ws;
    float4* pts  = (float4*)((char*)d_ws + WS_PTS_OFF);
    int*    idxw = (int*)((char*)d_ws + WS_IDX_OFF);
    float*  dwl  = (float*)((char*)d_ws + WS_DWL_OFF);
    float*  outp = (float*)d_out;

    hipLaunchKernelGGL(bn_prep, dim3(1), dim3(1024), 0, stream,
                       bnpf1, bnpf2, bnc1, bnc2, bnc3, bnf,
                       Wpf1, bpf1, Wpf2, bpf2, wsf);
    hipLaunchKernelGGL(pack_pts, dim3((B_ * NIN_ + 255) / 256), dim3(256), 0, stream,
                       inp, pts);
    hipLaunchKernelGGL(knn_kernel, dim3((B_ * P_) / 4), dim3(256), 0, stream,
                       pts, idxw);
    hipLaunchKernelGGL(p1_kernel, dim3((B_ * P_) / 4), dim3(256), 0, stream,
                       inp, idxw, Wc1, bc1, Wc2, bc2, Wc3, bc3, Wdf, wsf,
                       dwl, outp);
    hipLaunchKernelGGL(pw_kernel, dim3((B_ * P_) / 32), dim3(256), 0, stream,
                       dwl, Wpw, bf, wsf, outp);
}